// Round 3
// baseline (1919.496 us; speedup 1.0000x reference)
//
#include <hip/hip_runtime.h>
#include <hip/hip_bf16.h>
#include <stdint.h>

#define DM 1024
#define DF 4096
#define NE 8
#define TT 16384
#define CAP 33792      // 264 tiles * 128 rows max padded entries
#define MAXTILES 264

typedef __bf16 bf16;
typedef __attribute__((ext_vector_type(8))) __bf16 bf16x8;
typedef __attribute__((ext_vector_type(4))) __bf16 bf16x4;
typedef __attribute__((ext_vector_type(4))) float f32x4;

#define AS1 __attribute__((address_space(1)))
#define AS3 __attribute__((address_space(3)))

__device__ __forceinline__ void async16(void* lds, const void* g) {
  __builtin_amdgcn_global_load_lds((const AS1 uint32_t*)g, (AS3 uint32_t*)lds, 16, 0, 0);
}

// ---------------- router: logits + top2 + softmax2 (pure f32, exact) --------
__global__ void k_gate(const float* __restrict__ x, const float* __restrict__ gw,
                       const float* __restrict__ gb,
                       int* __restrict__ sel, float* __restrict__ cw,
                       int* __restrict__ counts) {
  int gid = blockIdx.x * blockDim.x + threadIdx.x;
  int tok = gid >> 6;
  int lane = threadIdx.x & 63;
  const float* xr = x + (size_t)tok * DM;
  float l[8] = {0,0,0,0,0,0,0,0};
#pragma unroll
  for (int i = 0; i < DM / 64; i++) {
    int d = i * 64 + lane;
    float xv = xr[d];
    float4 gA = *(const float4*)(gw + d * 8);
    float4 gB = *(const float4*)(gw + d * 8 + 4);
    l[0] += xv * gA.x; l[1] += xv * gA.y; l[2] += xv * gA.z; l[3] += xv * gA.w;
    l[4] += xv * gB.x; l[5] += xv * gB.y; l[6] += xv * gB.z; l[7] += xv * gB.w;
  }
#pragma unroll
  for (int e = 0; e < 8; e++) {
    float v = l[e];
    v += __shfl_xor(v, 1);  v += __shfl_xor(v, 2);  v += __shfl_xor(v, 4);
    v += __shfl_xor(v, 8);  v += __shfl_xor(v, 16); v += __shfl_xor(v, 32);
    l[e] = v + gb[e];
  }
  if (lane == 0) {
    int e0 = 0;
#pragma unroll
    for (int e = 1; e < 8; e++) if (l[e] > l[e0]) e0 = e;
    int e1 = (e0 == 0) ? 1 : 0;
#pragma unroll
    for (int e = 0; e < 8; e++) if (e != e1 && e != e0 && l[e] > l[e1]) e1 = e;
    float t = expf(l[e1] - l[e0]);      // <= 1
    float c0 = 1.0f / (1.0f + t);
    float c1 = t / (1.0f + t);
    sel[2 * tok] = e0;  sel[2 * tok + 1] = e1;
    cw[2 * tok] = c0;   cw[2 * tok + 1] = c1;
    atomicAdd(&counts[e0], 1);
    atomicAdd(&counts[e1], 1);
  }
}

// meta layout (ints): [0..7]=counts [8..15]=cursors [16..23]=segment offsets
//                     [24]=ntiles [25]=total_padded
//                     [64 .. 64+MAXTILES)  = tile expert id
//                     [64+MAXTILES .. )    = tile row0 (padded global row)
__global__ void k_plan(int* __restrict__ meta, int* __restrict__ rows) {
  if (threadIdx.x == 0) {
    int off = 0, nt = 0;
    for (int e = 0; e < NE; e++) {
      meta[16 + e] = off;
      int c = meta[e];
      int ntile = (c + 127) >> 7;
      for (int j = 0; j < ntile; j++) {
        meta[64 + nt] = e;
        meta[64 + MAXTILES + nt] = off + j * 128;
        nt++;
      }
      off += ntile * 128;
    }
    meta[24] = nt;
    meta[25] = off;
  }
  __syncthreads();
  for (int i = threadIdx.x; i < CAP; i += blockDim.x) rows[i] = -1;
}

__global__ void k_scatter(const int* __restrict__ sel, const float* __restrict__ cw,
                          int* __restrict__ meta, int* __restrict__ rows,
                          float* __restrict__ coefs) {
  int t = blockIdx.x * blockDim.x + threadIdx.x;
  if (t >= TT) return;
#pragma unroll
  for (int k = 0; k < 2; k++) {
    int e = sel[2 * t + k];
    int idx = atomicAdd(&meta[8 + e], 1);
    int pos = meta[16 + e] + idx;
    rows[pos] = t;
    coefs[pos] = cw[2 * t + k];
  }
}

__global__ void k_gather(const float* __restrict__ x, const int* __restrict__ rows,
                         const int* __restrict__ meta, bf16* __restrict__ xg) {
  int pos = blockIdx.x;
  if (pos >= meta[25]) return;
  int t = rows[pos];
  int c = threadIdx.x * 4;
  bf16x4 o;
  if (t >= 0) {
    float4 f = *(const float4*)(x + (size_t)t * DM + c);
    o[0] = (bf16)f.x; o[1] = (bf16)f.y; o[2] = (bf16)f.z; o[3] = (bf16)f.w;
  } else {
    o[0] = (bf16)0.0f; o[1] = (bf16)0.0f; o[2] = (bf16)0.0f; o[3] = (bf16)0.0f;
  }
  *(bf16x4*)(xg + (size_t)pos * DM + c) = o;
}

// reads src[z*srcE + (r0+r)*srcRS + c0+c]  (R rows, grid.x*64 cols)
// writes dst[z*dstE + (c0+c)*R + r0+r]  bf16   (transpose + cast)
__global__ void k_transcast(const float* __restrict__ src, bf16* __restrict__ dst,
                            int srcRS, size_t srcE, size_t dstE, int R) {
  __shared__ float tile[64][65];
  src += blockIdx.z * srcE;
  dst += blockIdx.z * dstE;
  int r0 = blockIdx.y * 64, c0 = blockIdx.x * 64;
  int tr = threadIdx.x >> 4;          // 0..15
  int tc = (threadIdx.x & 15) * 4;    // 0..60
#pragma unroll
  for (int i = 0; i < 4; i++) {
    int r = tr + i * 16;
    float4 f = *(const float4*)(src + (size_t)(r0 + r) * srcRS + (c0 + tc));
    tile[r][tc] = f.x; tile[r][tc + 1] = f.y; tile[r][tc + 2] = f.z; tile[r][tc + 3] = f.w;
  }
  __syncthreads();
#pragma unroll
  for (int i = 0; i < 4; i++) {
    int cc = tr + i * 16;             // output row = input col
    bf16x4 o;
    o[0] = (bf16)tile[tc + 0][cc];
    o[1] = (bf16)tile[tc + 1][cc];
    o[2] = (bf16)tile[tc + 2][cc];
    o[3] = (bf16)tile[tc + 3][cc];
    *(bf16x4*)(dst + (size_t)(c0 + cc) * R + (r0 + tc)) = o;
  }
}

// grouped GEMM, 128x128 tile, BK=64, 4 waves (2x2), 16x16x32 bf16 MFMA
// MODE 0: H[gr][n] = silu(acc + bias[e*bstride + n0+gc])   (bf16, row stride NT)
// MODE 1: atomicAdd(out[token][n], coef * (acc + addBias?bias:0)), token = rows[gr]
template<int MODE>
__global__ __launch_bounds__(256) void k_gemm(
    const bf16* __restrict__ A, const bf16* __restrict__ Bw,
    const float* __restrict__ bias, int bstride,
    bf16* __restrict__ H, float* __restrict__ Out, int addBias,
    const int* __restrict__ rows, const float* __restrict__ coefs,
    const int* __restrict__ meta, int KT, int NT) {
  int tidb = blockIdx.y;
  if (tidb >= meta[24]) return;
  int e = meta[64 + tidb];
  int row0 = meta[64 + MAXTILES + tidb];
  int n0 = blockIdx.x * 128;

  __shared__ __align__(16) bf16 As[128 * 64];
  __shared__ __align__(16) bf16 Bs[128 * 64];

  int t = threadIdx.x;
  int lane = t & 63;
  int wave = t >> 6;
  int wr = (wave >> 1) * 64, wc = (wave & 1) * 64;

  int mstage = t >> 3;          // 0..31
  int kstage = (t & 7) * 8;
  const bf16* Ab = A + ((size_t)row0 + mstage) * KT + kstage;
  const bf16* Bb = Bw + ((size_t)e * NT + n0 + mstage) * KT + kstage;
  int ldso = t * 8;             // element offset in LDS for staging

  f32x4 acc[4][4] = {};

  for (int kt = 0; kt < KT; kt += 64) {
    __syncthreads();
#pragma unroll
    for (int i = 0; i < 4; i++)
      async16(&As[ldso + i * 2048], Ab + kt + (size_t)i * 32 * KT);
#pragma unroll
    for (int i = 0; i < 4; i++)
      async16(&Bs[ldso + i * 2048], Bb + kt + (size_t)i * 32 * KT);
    __syncthreads();   // compiler drains vmcnt before s_barrier
#pragma unroll
    for (int ks = 0; ks < 2; ks++) {
      int ko = ks * 32 + (lane >> 4) * 8;
      bf16x8 af[4], bfr[4];
#pragma unroll
      for (int mi = 0; mi < 4; mi++)
        af[mi] = *(const bf16x8*)&As[(wr + mi * 16 + (lane & 15)) * 64 + ko];
#pragma unroll
      for (int ni = 0; ni < 4; ni++)
        bfr[ni] = *(const bf16x8*)&Bs[(wc + ni * 16 + (lane & 15)) * 64 + ko];
#pragma unroll
      for (int mi = 0; mi < 4; mi++)
#pragma unroll
        for (int ni = 0; ni < 4; ni++)
          acc[mi][ni] = __builtin_amdgcn_mfma_f32_16x16x32_bf16(af[mi], bfr[ni], acc[mi][ni], 0, 0, 0);
    }
  }

  int rq = (lane >> 4) * 4;
  int cq = lane & 15;
  if (MODE == 0) {
#pragma unroll
    for (int mi = 0; mi < 4; mi++) {
#pragma unroll
      for (int i = 0; i < 4; i++) {
        int gr = row0 + wr + mi * 16 + rq + i;
        bf16* hr = H + (size_t)gr * NT + n0;
#pragma unroll
        for (int ni = 0; ni < 4; ni++) {
          int gc = wc + ni * 16 + cq;
          float v = acc[mi][ni][i] + bias[e * bstride + n0 + gc];
          float s = v / (1.0f + __expf(-v));
          hr[gc] = (bf16)s;
        }
      }
    }
  } else {
#pragma unroll
    for (int mi = 0; mi < 4; mi++) {
#pragma unroll
      for (int i = 0; i < 4; i++) {
        int gr = row0 + wr + mi * 16 + rq + i;
        int trow = rows[gr];
        if (trow < 0) continue;
        float cf = coefs[gr];
        float* orow = Out + (size_t)trow * DM + n0;
#pragma unroll
        for (int ni = 0; ni < 4; ni++) {
          int gc = wc + ni * 16 + cq;
          float v = acc[mi][ni][i];
          if (addBias) v += bias[e * bstride + n0 + gc];
          atomicAdd(&orow[gc], cf * v);
        }
      }
    }
  }
}

extern "C" void kernel_launch(void* const* d_in, const int* in_sizes, int n_in,
                              void* d_out, int out_size, void* d_ws, size_t ws_size,
                              hipStream_t stream) {
  const float* x  = (const float*)d_in[0];
  const float* gw = (const float*)d_in[1];
  const float* gb = (const float*)d_in[2];
  const float* w1 = (const float*)d_in[3];
  const float* b1 = (const float*)d_in[4];
  const float* w2 = (const float*)d_in[5];
  const float* b2 = (const float*)d_in[6];
  float* out = (float*)d_out;

  // pick DF chunking so the workspace plan fits ws_size
  size_t smallB = (size_t)CAP * 4 * 2 + (size_t)TT * 2 * 4 * 2 + 8192 + 16 * 256;
  int nc = 8;
  for (int cand = 1; cand <= 8; cand <<= 1) {
    size_t dfc = DF / cand;
    size_t need = 2 * ((size_t)NE * dfc * DM * 2)   // w1tc + w2tc
                + (size_t)CAP * DM * 2              // xg
                + (size_t)CAP * dfc * 2             // h
                + smallB;
    if (need <= ws_size) { nc = cand; break; }
  }
  const int DFC = DF / nc;

  char* ws = (char*)d_ws;
  size_t off = 0;
  auto alloc = [&](size_t bytes) -> void* {
    void* p = ws + off;
    off += (bytes + 255) & ~(size_t)255;
    return p;
  };
  bf16* w1tc = (bf16*)alloc((size_t)NE * DFC * DM * 2);  // [E][DFC][DM]
  bf16* w2tc = (bf16*)alloc((size_t)NE * DM * DFC * 2);  // [E][DM][DFC]
  bf16* xg   = (bf16*)alloc((size_t)CAP * DM * 2);
  bf16* h    = (bf16*)alloc((size_t)CAP * DFC * 2);
  int* rows  = (int*)alloc((size_t)CAP * 4);
  float* cof = (float*)alloc((size_t)CAP * 4);
  int* sel   = (int*)alloc((size_t)TT * 2 * 4);
  float* cw  = (float*)alloc((size_t)TT * 2 * 4);
  int* meta  = (int*)alloc(8192);

  hipMemsetAsync(meta, 0, 256, stream);
  hipMemsetAsync(out, 0, (size_t)out_size * sizeof(float), stream);
  k_gate<<<TT / 4, 256, 0, stream>>>(x, gw, gb, sel, cw, meta);
  k_plan<<<1, 256, 0, stream>>>(meta, rows);
  k_scatter<<<TT / 256, 256, 0, stream>>>(sel, cw, meta, rows, cof);
  k_gather<<<CAP, 256, 0, stream>>>(x, rows, meta, xg);

  for (int c = 0; c < nc; c++) {
    const float* w1c = w1 + (size_t)c * DFC;        // [E][DM][DF] cols c*DFC..
    const float* w2c = w2 + (size_t)c * DFC * DM;   // [E][DF][DM] rows c*DFC..
    // w1 chunk: R=DM rows, DFC cols -> w1tc [E][DFC][DM]
    k_transcast<<<dim3(DFC / 64, DM / 64, NE), 256, 0, stream>>>(
        w1c, w1tc, DF, (size_t)DM * DF, (size_t)DFC * DM, DM);
    // w2 chunk: R=DFC rows, DM cols -> w2tc [E][DM][DFC]
    k_transcast<<<dim3(DM / 64, DFC / 64, NE), 256, 0, stream>>>(
        w2c, w2tc, DM, (size_t)DF * DM, (size_t)DM * DFC, DFC);
    // GEMM1: [CAP rows] x [DM] @ [DM x DFC] -> h (silu)
    k_gemm<0><<<dim3(DFC / 128, MAXTILES), 256, 0, stream>>>(
        xg, w1tc, b1 + (size_t)c * DFC, DF, h, nullptr, 0, rows, cof, meta, DM, DFC);
    // GEMM2: [CAP rows] x [DFC] @ [DFC x DM] -> atomic out
    k_gemm<1><<<dim3(DM / 128, MAXTILES), 256, 0, stream>>>(
        h, w2tc, b2, DM, nullptr, out, (c == 0) ? 1 : 0, rows, cof, meta, DFC, DM);
  }
}

// Round 4
// 1576.556 us; speedup vs baseline: 1.2175x; 1.2175x over previous
//
#include <hip/hip_runtime.h>
#include <hip/hip_bf16.h>
#include <stdint.h>

#define DM 1024
#define DF 4096
#define NE 8
#define TT 16384
#define CAP 33792      // 264 tiles * 128 rows max padded entries
#define MAXTILES 264

typedef __bf16 bf16;
typedef __attribute__((ext_vector_type(8))) __bf16 bf16x8;
typedef __attribute__((ext_vector_type(4))) __bf16 bf16x4;
typedef __attribute__((ext_vector_type(4))) float f32x4;

#define AS1 __attribute__((address_space(1)))
#define AS3 __attribute__((address_space(3)))

__device__ __forceinline__ void async16(void* lds, const void* g) {
  __builtin_amdgcn_global_load_lds((const AS1 uint32_t*)g, (AS3 uint32_t*)lds, 16, 0, 0);
}

// ---------------- router: logits + top2 + softmax2 (pure f32, exact) --------
__global__ void k_gate(const float* __restrict__ x, const float* __restrict__ gw,
                       const float* __restrict__ gb,
                       int* __restrict__ sel, float* __restrict__ cw,
                       int* __restrict__ counts) {
  int gid = blockIdx.x * blockDim.x + threadIdx.x;
  int tok = gid >> 6;
  int lane = threadIdx.x & 63;
  const float* xr = x + (size_t)tok * DM;
  float l[8] = {0,0,0,0,0,0,0,0};
#pragma unroll
  for (int i = 0; i < DM / 64; i++) {
    int d = i * 64 + lane;
    float xv = xr[d];
    float4 gA = *(const float4*)(gw + d * 8);
    float4 gB = *(const float4*)(gw + d * 8 + 4);
    l[0] += xv * gA.x; l[1] += xv * gA.y; l[2] += xv * gA.z; l[3] += xv * gA.w;
    l[4] += xv * gB.x; l[5] += xv * gB.y; l[6] += xv * gB.z; l[7] += xv * gB.w;
  }
#pragma unroll
  for (int e = 0; e < 8; e++) {
    float v = l[e];
    v += __shfl_xor(v, 1);  v += __shfl_xor(v, 2);  v += __shfl_xor(v, 4);
    v += __shfl_xor(v, 8);  v += __shfl_xor(v, 16); v += __shfl_xor(v, 32);
    l[e] = v + gb[e];
  }
  if (lane == 0) {
    int e0 = 0;
#pragma unroll
    for (int e = 1; e < 8; e++) if (l[e] > l[e0]) e0 = e;
    int e1 = (e0 == 0) ? 1 : 0;
#pragma unroll
    for (int e = 0; e < 8; e++) if (e != e1 && e != e0 && l[e] > l[e1]) e1 = e;
    float t = expf(l[e1] - l[e0]);      // <= 1
    float c0 = 1.0f / (1.0f + t);
    float c1 = t / (1.0f + t);
    sel[2 * tok] = e0;  sel[2 * tok + 1] = e1;
    cw[2 * tok] = c0;   cw[2 * tok + 1] = c1;
    atomicAdd(&counts[e0], 1);
    atomicAdd(&counts[e1], 1);
  }
}

// meta layout (ints): [0..7]=counts [8..15]=cursors [16..23]=segment offsets
//                     [24]=ntiles [25]=total_padded
//                     [64 .. 64+MAXTILES)  = tile expert id
//                     [64+MAXTILES .. )    = tile row0 (padded global row)
__global__ void k_plan(int* __restrict__ meta, int* __restrict__ rows) {
  if (threadIdx.x == 0) {
    int off = 0, nt = 0;
    for (int e = 0; e < NE; e++) {
      meta[16 + e] = off;
      int c = meta[e];
      int ntile = (c + 127) >> 7;
      for (int j = 0; j < ntile; j++) {
        meta[64 + nt] = e;
        meta[64 + MAXTILES + nt] = off + j * 128;
        nt++;
      }
      off += ntile * 128;
    }
    meta[24] = nt;
    meta[25] = off;
  }
  __syncthreads();
  for (int i = threadIdx.x; i < CAP; i += blockDim.x) rows[i] = -1;
}

__global__ void k_scatter(const int* __restrict__ sel, const float* __restrict__ cw,
                          int* __restrict__ meta, int* __restrict__ rows,
                          float* __restrict__ coefs) {
  int t = blockIdx.x * blockDim.x + threadIdx.x;
  if (t >= TT) return;
#pragma unroll
  for (int k = 0; k < 2; k++) {
    int e = sel[2 * t + k];
    int idx = atomicAdd(&meta[8 + e], 1);
    int pos = meta[16 + e] + idx;
    rows[pos] = t;
    coefs[pos] = cw[2 * t + k];
  }
}

__global__ void k_gather(const float* __restrict__ x, const int* __restrict__ rows,
                         const int* __restrict__ meta, bf16* __restrict__ xg) {
  int pos = blockIdx.x;
  if (pos >= meta[25]) return;
  int t = rows[pos];
  int c = threadIdx.x * 4;
  bf16x4 o;
  if (t >= 0) {
    float4 f = *(const float4*)(x + (size_t)t * DM + c);
    o[0] = (bf16)f.x; o[1] = (bf16)f.y; o[2] = (bf16)f.z; o[3] = (bf16)f.w;
  } else {
    o[0] = (bf16)0.0f; o[1] = (bf16)0.0f; o[2] = (bf16)0.0f; o[3] = (bf16)0.0f;
  }
  *(bf16x4*)(xg + (size_t)pos * DM + c) = o;
}

// reads src[z*srcE + (r0+r)*srcRS + c0+c]  (R rows, grid.x*64 cols)
// writes dst[z*dstE + (c0+c)*R + r0+r]  bf16   (transpose + cast)
__global__ void k_transcast(const float* __restrict__ src, bf16* __restrict__ dst,
                            int srcRS, size_t srcE, size_t dstE, int R) {
  __shared__ float tile[64][65];
  src += blockIdx.z * srcE;
  dst += blockIdx.z * dstE;
  int r0 = blockIdx.y * 64, c0 = blockIdx.x * 64;
  int tr = threadIdx.x >> 4;          // 0..15
  int tc = (threadIdx.x & 15) * 4;    // 0..60
#pragma unroll
  for (int i = 0; i < 4; i++) {
    int r = tr + i * 16;
    float4 f = *(const float4*)(src + (size_t)(r0 + r) * srcRS + (c0 + tc));
    tile[r][tc] = f.x; tile[r][tc + 1] = f.y; tile[r][tc + 2] = f.z; tile[r][tc + 3] = f.w;
  }
  __syncthreads();
#pragma unroll
  for (int i = 0; i < 4; i++) {
    int cc = tr + i * 16;             // output row = input col
    bf16x4 o;
    o[0] = (bf16)tile[tc + 0][cc];
    o[1] = (bf16)tile[tc + 1][cc];
    o[2] = (bf16)tile[tc + 2][cc];
    o[3] = (bf16)tile[tc + 3][cc];
    *(bf16x4*)(dst + (size_t)(c0 + cc) * R + (r0 + tc)) = o;
  }
}

// grouped GEMM, 128x128 tile, BK=64, 4 waves (2x2), 16x16x32 bf16 MFMA
// LDS tiles are XOR-swizzled (T2): element k of row r is stored at
// r*64 + (k ^ ((r&7)*8)). global_load_lds writes linearly, so the GLOBAL
// source k-offset is pre-swizzled (rule #21: both-sides-or-neither).
// MODE 0: H[gr][n] = silu(acc + bias)   (bf16, row stride NT)
// MODE 1: atomicAdd(out[token][n], coef * (acc + addBias?bias:0))
template<int MODE>
__global__ __launch_bounds__(256) void k_gemm(
    const bf16* __restrict__ A, const bf16* __restrict__ Bw,
    const float* __restrict__ bias, int bstride,
    bf16* __restrict__ H, float* __restrict__ Out, int addBias,
    const int* __restrict__ rows, const float* __restrict__ coefs,
    const int* __restrict__ meta, int KT, int NT) {
  int tidb = blockIdx.y;
  if (tidb >= meta[24]) return;
  int e = meta[64 + tidb];
  int row0 = meta[64 + MAXTILES + tidb];
  int n0 = blockIdx.x * 128;

  __shared__ __align__(16) bf16 As[128 * 64];
  __shared__ __align__(16) bf16 Bs[128 * 64];

  int t = threadIdx.x;
  int lane = t & 63;
  int wave = t >> 6;
  int wr = (wave >> 1) * 64, wc = (wave & 1) * 64;

  int mstage = t >> 3;                                  // staging row 0..31
  int kswz = ((t & 7) ^ (mstage & 7)) * 8;              // pre-swizzled src k
  const bf16* Ab = A + ((size_t)row0 + mstage) * KT + kswz;
  const bf16* Bb = Bw + ((size_t)e * NT + n0 + mstage) * KT + kswz;
  int ldso = t * 8;             // linear LDS element offset for staging

  f32x4 acc[4][4] = {};

  for (int kt = 0; kt < KT; kt += 64) {
    __syncthreads();
#pragma unroll
    for (int i = 0; i < 4; i++)
      async16(&As[ldso + i * 2048], Ab + kt + (size_t)i * 32 * KT);
#pragma unroll
    for (int i = 0; i < 4; i++)
      async16(&Bs[ldso + i * 2048], Bb + kt + (size_t)i * 32 * KT);
    __syncthreads();   // compiler drains vmcnt before s_barrier
#pragma unroll
    for (int ks = 0; ks < 2; ks++) {
      int ko = ks * 32 + (lane >> 4) * 8;
      int kx = ko ^ ((lane & 7) * 8);   // row&7 == lane&7 for all fragments
      bf16x8 af[4], bfr[4];
#pragma unroll
      for (int mi = 0; mi < 4; mi++)
        af[mi] = *(const bf16x8*)&As[(wr + mi * 16 + (lane & 15)) * 64 + kx];
#pragma unroll
      for (int ni = 0; ni < 4; ni++)
        bfr[ni] = *(const bf16x8*)&Bs[(wc + ni * 16 + (lane & 15)) * 64 + kx];
#pragma unroll
      for (int mi = 0; mi < 4; mi++)
#pragma unroll
        for (int ni = 0; ni < 4; ni++)
          acc[mi][ni] = __builtin_amdgcn_mfma_f32_16x16x32_bf16(af[mi], bfr[ni], acc[mi][ni], 0, 0, 0);
    }
  }

  int rq = (lane >> 4) * 4;
  int cq = lane & 15;
  float bv[4];
#pragma unroll
  for (int ni = 0; ni < 4; ni++)
    bv[ni] = bias[e * bstride + n0 + wc + ni * 16 + cq];

  if (MODE == 0) {
#pragma unroll
    for (int mi = 0; mi < 4; mi++) {
#pragma unroll
      for (int i = 0; i < 4; i++) {
        int gr = row0 + wr + mi * 16 + rq + i;
        bf16* hr = H + (size_t)gr * NT + n0;
#pragma unroll
        for (int ni = 0; ni < 4; ni++) {
          int gc = wc + ni * 16 + cq;
          float v = acc[mi][ni][i] + bv[ni];
          float s = v / (1.0f + __expf(-v));
          hr[gc] = (bf16)s;
        }
      }
    }
  } else {
#pragma unroll
    for (int mi = 0; mi < 4; mi++) {
#pragma unroll
      for (int i = 0; i < 4; i++) {
        int gr = row0 + wr + mi * 16 + rq + i;
        int trow = rows[gr];
        if (trow < 0) continue;
        float cf = coefs[gr];
        float* orow = Out + (size_t)trow * DM + n0;
#pragma unroll
        for (int ni = 0; ni < 4; ni++) {
          int gc = wc + ni * 16 + cq;
          float v = acc[mi][ni][i];
          if (addBias) v += bv[ni];
          atomicAdd(&orow[gc], cf * v);
        }
      }
    }
  }
}

extern "C" void kernel_launch(void* const* d_in, const int* in_sizes, int n_in,
                              void* d_out, int out_size, void* d_ws, size_t ws_size,
                              hipStream_t stream) {
  const float* x  = (const float*)d_in[0];
  const float* gw = (const float*)d_in[1];
  const float* gb = (const float*)d_in[2];
  const float* w1 = (const float*)d_in[3];
  const float* b1 = (const float*)d_in[4];
  const float* w2 = (const float*)d_in[5];
  const float* b2 = (const float*)d_in[6];
  float* out = (float*)d_out;

  // pick DF chunking so the workspace plan fits ws_size
  size_t smallB = (size_t)CAP * 4 * 2 + (size_t)TT * 2 * 4 * 2 + 8192 + 16 * 256;
  int nc = 8;
  for (int cand = 1; cand <= 8; cand <<= 1) {
    size_t dfc = DF / cand;
    size_t need = 2 * ((size_t)NE * dfc * DM * 2)   // w1tc + w2tc
                + (size_t)CAP * DM * 2              // xg
                + (size_t)CAP * dfc * 2             // h
                + smallB;
    if (need <= ws_size) { nc = cand; break; }
  }
  const int DFC = DF / nc;

  char* ws = (char*)d_ws;
  size_t off = 0;
  auto alloc = [&](size_t bytes) -> void* {
    void* p = ws + off;
    off += (bytes + 255) & ~(size_t)255;
    return p;
  };
  bf16* w1tc = (bf16*)alloc((size_t)NE * DFC * DM * 2);  // [E][DFC][DM]
  bf16* w2tc = (bf16*)alloc((size_t)NE * DM * DFC * 2);  // [E][DM][DFC]
  bf16* xg   = (bf16*)alloc((size_t)CAP * DM * 2);
  bf16* h    = (bf16*)alloc((size_t)CAP * DFC * 2);
  int* rows  = (int*)alloc((size_t)CAP * 4);
  float* cof = (float*)alloc((size_t)CAP * 4);
  int* sel   = (int*)alloc((size_t)TT * 2 * 4);
  float* cw  = (float*)alloc((size_t)TT * 2 * 4);
  int* meta  = (int*)alloc(8192);

  hipMemsetAsync(meta, 0, 256, stream);
  hipMemsetAsync(out, 0, (size_t)out_size * sizeof(float), stream);
  k_gate<<<TT / 4, 256, 0, stream>>>(x, gw, gb, sel, cw, meta);
  k_plan<<<1, 256, 0, stream>>>(meta, rows);
  k_scatter<<<TT / 256, 256, 0, stream>>>(sel, cw, meta, rows, cof);
  k_gather<<<CAP, 256, 0, stream>>>(x, rows, meta, xg);

  for (int c = 0; c < nc; c++) {
    const float* w1c = w1 + (size_t)c * DFC;        // [E][DM][DF] cols c*DFC..
    const float* w2c = w2 + (size_t)c * DFC * DM;   // [E][DF][DM] rows c*DFC..
    // w1 chunk: R=DM rows, DFC cols -> w1tc [E][DFC][DM]
    k_transcast<<<dim3(DFC / 64, DM / 64, NE), 256, 0, stream>>>(
        w1c, w1tc, DF, (size_t)DM * DF, (size_t)DFC * DM, DM);
    // w2 chunk: R=DFC rows, DM cols -> w2tc [E][DM][DFC]
    k_transcast<<<dim3(DM / 64, DFC / 64, NE), 256, 0, stream>>>(
        w2c, w2tc, DM, (size_t)DF * DM, (size_t)DM * DFC, DFC);
    // GEMM1: [CAP rows] x [DM] @ [DM x DFC] -> h (silu)
    k_gemm<0><<<dim3(DFC / 128, MAXTILES), 256, 0, stream>>>(
        xg, w1tc, b1 + (size_t)c * DFC, DF, h, nullptr, 0, rows, cof, meta, DM, DFC);
    // GEMM2: [CAP rows] x [DFC] @ [DFC x DM] -> atomic out
    k_gemm<1><<<dim3(DM / 128, MAXTILES), 256, 0, stream>>>(
        h, w2tc, b2, DM, nullptr, out, (c == 0) ? 1 : 0, rows, cof, meta, DFC, DM);
  }
}